// Round 11
// baseline (148.693 us; speedup 1.0000x reference)
//
#include <hip/hip_runtime.h>
#include <hip/hip_bf16.h>
#include <stdint.h>

// AnchorAttention on MI355X. Inputs/outputs fp32; internal compute bf16 MFMA + fp32 accum.
// Pipeline: ln_fused -> cvt weights -> gemm<0> QKA+V^T (BK=64) -> flash10 x2 (2-tile bodies)
//           -> gemm<1> (BK=64).

using bf16 = __bf16;
typedef __bf16 bf16x4 __attribute__((ext_vector_type(4)));
typedef __bf16 bf16x8 __attribute__((ext_vector_type(8)));
typedef float f32x4 __attribute__((ext_vector_type(4)));
typedef float f32x16 __attribute__((ext_vector_type(16)));

#define DIMC 512
#define NTOK 1024
#define NB 8
#define NH 8
#define HD 64

__device__ __forceinline__ void gload_lds16(const bf16* g, bf16* l) {
  __builtin_amdgcn_global_load_lds((__attribute__((address_space(1))) void*)g,
                                   (__attribute__((address_space(3))) void*)l,
                                   16, 0, 0);
}

__device__ __forceinline__ float bpermf(int srclane, float v) {
  int i = __builtin_amdgcn_ds_bpermute(srclane << 2, __builtin_bit_cast(int, v));
  return __builtin_bit_cast(float, i);
}

__device__ __forceinline__ int pkbf(float lo, float hi) {
  unsigned short a = __builtin_bit_cast(unsigned short, (bf16)lo);
  unsigned short b = __builtin_bit_cast(unsigned short, (bf16)hi);
  return (int)((unsigned)a | ((unsigned)b << 16));
}

// raw v_exp_f32: exact 2^x
__device__ __forceinline__ float fexp2(float x) {
  float r;
  asm("v_exp_f32 %0, %1" : "=v"(r) : "v"(x));
  return r;
}

// ---------------- fused LN: stats + apply + transpose ----------------
__global__ __launch_bounds__(256) void k_ln_fused(
    const float* __restrict__ r, const float* __restrict__ z,
    const float* __restrict__ wr, const float* __restrict__ br,
    const float* __restrict__ wz, const float* __restrict__ bz,
    bf16* __restrict__ rf, bf16* __restrict__ zf) {
  __shared__ float sp[4][64], ssq[4][64];
  __shared__ float muS[64], rsS[64];
  __shared__ __align__(16) bf16 T[64 * 72];
  int n0 = blockIdx.x * 64, b = blockIdx.y, tensor = blockIdx.z;
  const float* x   = tensor ? z  : r;
  const float* w   = tensor ? wz : wr;
  const float* bia = tensor ? bz : br;
  bf16* out = tensor ? zf : rf;
  int tid = threadIdx.x;

  {
    int n = tid & 63, grp = tid >> 6;
    const float* xp = x + ((size_t)(b * DIMC + grp * 128)) * NTOK + n0 + n;
    float s = 0.f, ss = 0.f;
#pragma unroll 8
    for (int c = 0; c < 128; ++c) {
      float v = xp[(size_t)c * NTOK];
      s += v; ss += v * v;
    }
    sp[grp][n] = s; ssq[grp][n] = ss;
  }
  __syncthreads();
  if (tid < 64) {
    float s  = sp[0][tid] + sp[1][tid] + sp[2][tid] + sp[3][tid];
    float ss = ssq[0][tid] + ssq[1][tid] + ssq[2][tid] + ssq[3][tid];
    float m = s * (1.0f / DIMC);
    muS[tid] = m;
    rsS[tid] = rsqrtf(ss * (1.0f / DIMC) - m * m + 1e-5f);
  }
  __syncthreads();

  int cl = tid >> 3;
  int nl = (tid & 7) * 8;
  for (int cs = 0; cs < 8; ++cs) {
    int c0 = cs * 64;
#pragma unroll
    for (int pass = 0; pass < 2; ++pass) {
      int c = c0 + pass * 32 + cl;
      float wc = w[c], bc = bia[c];
      const float* src = x + ((size_t)(b * DIMC + c)) * NTOK + n0 + nl;
      float4 v0 = *reinterpret_cast<const float4*>(src);
      float4 v1 = *reinterpret_cast<const float4*>(src + 4);
      float vv[8] = {v0.x, v0.y, v0.z, v0.w, v1.x, v1.y, v1.z, v1.w};
#pragma unroll
      for (int j = 0; j < 8; ++j) {
        int n = nl + j;
        float val = (vv[j] - muS[n]) * rsS[n] * wc + bc;
        T[n * 72 + pass * 32 + cl] = (bf16)val;
      }
    }
    __syncthreads();
#pragma unroll
    for (int pass = 0; pass < 2; ++pass) {
      int n = pass * 32 + cl;
      bf16x8 o;
#pragma unroll
      for (int j = 0; j < 8; ++j) o[j] = T[n * 72 + nl + j];
      *reinterpret_cast<bf16x8*>(out + ((size_t)(b * NTOK + n0 + n)) * DIMC + c0 + nl) = o;
    }
    __syncthreads();
  }
}

// ---------------- weight convert fp32 -> bf16, 5 matrices ----------------
__global__ __launch_bounds__(256) void k_cvt5(
    const float* __restrict__ W0, const float* __restrict__ W1,
    const float* __restrict__ W2, const float* __restrict__ W3,
    const float* __restrict__ W4, bf16* __restrict__ out) {
  int m = blockIdx.y;
  const float* W = (m == 0) ? W0 : (m == 1) ? W1 : (m == 2) ? W2 : (m == 3) ? W3 : W4;
  bf16* o = out + (size_t)m * DIMC * DIMC;
  int i = blockIdx.x * 256 + threadIdx.x;
  float4 v = reinterpret_cast<const float4*>(W)[i];
  bf16x4 b;
  b[0] = (bf16)v.x; b[1] = (bf16)v.y; b[2] = (bf16)v.z; b[3] = (bf16)v.w;
  *reinterpret_cast<bf16x4*>(o + (size_t)i * 4) = b;
}

// ---------------- GEMM (bt), 128x128 tile, BK=64 as two [128][32] LDS panels ----------------
// MODE 0: mat 0=Q 1=K 2=A (act x W -> qka[mat][b][h][n][d]); mat 3 = V^T (Wv x zf -> vt[b][d][n])
// MODE 1: Wproj x at2 -> d_out[b][o][n] + bias + residual z (fp32)
template <int MODE>
__global__ __launch_bounds__(256) void k_gemm(
    const bf16* __restrict__ actA, const bf16* __restrict__ zf,
    const bf16* __restrict__ Wbf,
    void* __restrict__ outbase,
    const float* __restrict__ zres, const float* __restrict__ bproj) {
  __shared__ __align__(16) bf16 As[2 * 128 * 32];  // [panel s][row][32]
  __shared__ __align__(16) bf16 Bs[2 * 128 * 32];
  int b = blockIdx.z;
  const bf16 *Ap, *Bp;
  int m0, n0;
  int mat = (MODE == 0) ? blockIdx.y : -1;
  if (MODE == 0 && mat < 3) {
    Ap = (mat < 2 ? actA : zf) + (size_t)b * NTOK * DIMC;
    int widx = (mat == 2) ? 3 : mat;
    Bp = Wbf + (size_t)widx * DIMC * DIMC;
    m0 = (blockIdx.x >> 2) * 128;
    n0 = (blockIdx.x & 3) * 128;
  } else {
    Ap = Wbf + (size_t)(MODE == 1 ? 4 : 2) * DIMC * DIMC;
    Bp = (MODE == 1 ? actA : zf) + (size_t)b * NTOK * DIMC;
    m0 = (blockIdx.x >> 3) * 128;
    n0 = (blockIdx.x & 7) * 128;
  }
  int tid = threadIdx.x;
  int w = tid >> 6, l = tid & 63;
  int wm = (w >> 1) * 64, wn = (w & 1) * 64;
  int lr = l & 15, lg = l >> 4;
  int srow = l >> 2;
  int scol = (l & 3) * 8;
  f32x4 acc[4][4] = {};

  for (int kt = 0; kt < 8; ++kt) {
    int k0 = kt * 64;
#pragma unroll
    for (int s = 0; s < 2; ++s) {
#pragma unroll
      for (int q = 0; q < 2; ++q) {
        int rowA = w * 32 + q * 16 + srow;
        gload_lds16(Ap + (size_t)(m0 + rowA) * DIMC + k0 + s * 32 + scol,
                    &As[s * 4096 + (w * 32 + q * 16) * 32]);
        gload_lds16(Bp + (size_t)(n0 + rowA) * DIMC + k0 + s * 32 + scol,
                    &Bs[s * 4096 + (w * 32 + q * 16) * 32]);
      }
    }
    __syncthreads();
#pragma unroll
    for (int s = 0; s < 2; ++s) {
      bf16x8 af[4], bfr[4];
#pragma unroll
      for (int i = 0; i < 4; ++i)
        af[i] = *reinterpret_cast<const bf16x8*>(&As[s * 4096 + (wm + 16 * i + lr) * 32 + lg * 8]);
#pragma unroll
      for (int j = 0; j < 4; ++j)
        bfr[j] = *reinterpret_cast<const bf16x8*>(&Bs[s * 4096 + (wn + 16 * j + lr) * 32 + lg * 8]);
#pragma unroll
      for (int i = 0; i < 4; ++i)
#pragma unroll
        for (int j = 0; j < 4; ++j)
          acc[i][j] = __builtin_amdgcn_mfma_f32_16x16x32_bf16(af[i], bfr[j], acc[i][j], 0, 0, 0);
    }
    __syncthreads();
  }

  const size_t SLOT = (size_t)NB * NH * NTOK * HD;
#pragma unroll
  for (int i = 0; i < 4; ++i) {
#pragma unroll
    for (int j = 0; j < 4; ++j) {
#pragma unroll
      for (int rr = 0; rr < 4; ++rr) {
        int mm = m0 + wm + 16 * i + lg * 4 + rr;
        int nn = n0 + wn + 16 * j + lr;
        if (MODE == 0 && mat < 3) {
          bf16* outp = (bf16*)outbase + (size_t)mat * SLOT + (size_t)b * (NH * NTOK * HD);
          outp[((size_t)((nn >> 6) * NTOK + mm)) * HD + (nn & 63)] = (bf16)acc[i][j][rr];
        } else if (MODE == 0) {
          bf16* outp = (bf16*)outbase + 3 * SLOT + (size_t)b * DIMC * NTOK;
          outp[(size_t)mm * NTOK + nn] = (bf16)acc[i][j][rr];
        } else {
          float* outp = (float*)outbase + (size_t)b * DIMC * NTOK;
          const float* zp = zres + (size_t)b * DIMC * NTOK;
          size_t idx = (size_t)mm * NTOK + nn;
          outp[idx] = acc[i][j][rr] + bproj[mm] + zp[idx];
        }
      }
    }
  }
}

// ---------------- flash10: 2 KV-tiles per barrier body ----------------
// 4 warps x QBLK=32 (block = 128 q), KVBLK=64, 16 tiles processed as 8 bodies of 2 tiles.
// One barrier + one 32KB prefetch per body; two sequential 64-key sub-bodies reuse registers.
// Swapped QK^T; exp2 fixed max M=16 in MFMA C-init; fragment-linear LDS (conflict-free);
// 8-shuffle P exchange; deferred cross-half l-reduce.
// LDS 64KB: buf(half) = half*16384; within buf: sub*8192 + {K:0, V:4096}.
// grid 512: xcd=id&7, qt=(id>>3)&7, bh=((id&7)<<3)|(id>>6).
// out_mode 0: O^T -> [bh][d][n]; out_mode 1: [b][n][h*64+d].
__global__ __launch_bounds__(256) void k_flash10(
    const bf16* __restrict__ Qp, const bf16* __restrict__ Kp,
    const bf16* __restrict__ Vtp, bf16* __restrict__ Op, int out_mode) {
  __shared__ __align__(16) bf16 smem[32768];  // 64KB
  int tid = threadIdx.x;
  int w = tid >> 6, l = tid & 63;
  int hl = l >> 5, ln31 = l & 31;
  int id = blockIdx.x;
  int qt = (id >> 3) & 7;
  int bh = ((id & 7) << 3) | (id >> 6);
  int q0 = qt * 128;
  const bf16* Qb = Qp + (size_t)bh * NTOK * HD;
  const bf16* Kb = Kp + (size_t)bh * NTOK * HD;
  const bf16* Vb = Vtp + (size_t)bh * HD * NTOK;

  const float QS = 0.125f * 1.44269504088896340736f;
  bf16x8 qf[4];
  int qrow = q0 + w * 32 + ln31;
#pragma unroll
  for (int s = 0; s < 4; ++s) {
    bf16x8 raw = *reinterpret_cast<const bf16x8*>(Qb + (size_t)qrow * 64 + 16 * s + 8 * hl);
#pragma unroll
    for (int j = 0; j < 8; ++j) qf[s][j] = (bf16)((float)raw[j] * QS);
  }

  int koff0 = w * 16;
  int koff1 = w * 16 + 8;
  int fco = hl * 512 + ln31 * 8;

  // stage one 64-key tile into smem[dst..dst+8191] (K at +0, V at +4096)
  auto STAGE = [&](int tile, int dst) {
    int k0 = tile * 64;
    gload_lds16(Kb + (size_t)(k0 + l) * 64 + koff0, &smem[dst + (2 * w) * 512]);
    gload_lds16(Kb + (size_t)(k0 + l) * 64 + koff1, &smem[dst + (2 * w + 1) * 512]);
    gload_lds16(Vb + (size_t)l * 1024 + k0 + koff0, &smem[dst + 4096 + (2 * w) * 512]);
    gload_lds16(Vb + (size_t)l * 1024 + k0 + koff1, &smem[dst + 4096 + (2 * w + 1) * 512]);
  };

  // prologue: stage tiles 0,1 into buf 0
  STAGE(0, 0);
  STAGE(1, 8192);

  float l_run = 0.f;
  f32x16 of0{}, of1{};

#pragma unroll 1
  for (int bt = 0; bt < 8; ++bt) {
    __syncthreads();  // stage(body bt) ready; reads of buf(bt-1) complete
    int buf = (bt & 1) ? 16384 : 0;

    if (bt + 1 < 8) {
      int nb = buf ^ 16384;
      STAGE(2 * bt + 2, nb);
      STAGE(2 * bt + 3, nb + 8192);
    }

#pragma unroll
    for (int sub = 0; sub < 2; ++sub) {
      const bf16* Ks = &smem[buf + sub * 8192];
      const bf16* Vs = &smem[buf + sub * 8192 + 4096];

      bf16x8 kf0[4], kf1[4];
#pragma unroll
      for (int s = 0; s < 4; ++s) {
        kf0[s] = *reinterpret_cast<const bf16x8*>(&Ks[s * 1024 + fco]);
        kf1[s] = *reinterpret_cast<const bf16x8*>(&Ks[s * 1024 + fco + 256]);
      }

      f32x16 sT0, sT1;
#pragma unroll
      for (int r = 0; r < 16; ++r) { sT0[r] = -16.0f; sT1[r] = -16.0f; }
      __builtin_amdgcn_s_setprio(1);
#pragma unroll
      for (int s = 0; s < 4; ++s) {
        sT0 = __builtin_amdgcn_mfma_f32_32x32x16_bf16(kf0[s], qf[s], sT0, 0, 0, 0);
        sT1 = __builtin_amdgcn_mfma_f32_32x32x16_bf16(kf1[s], qf[s], sT1, 0, 0, 0);
      }
      __builtin_amdgcn_s_setprio(0);

      float s0 = 0.f, s1 = 0.f, s2 = 0.f, s3 = 0.f;
#pragma unroll
      for (int r = 0; r < 16; r += 4) {
        sT0[r]     = fexp2(sT0[r]);     s0 += sT0[r];
        sT0[r + 1] = fexp2(sT0[r + 1]); s1 += sT0[r + 1];
        sT0[r + 2] = fexp2(sT0[r + 2]); s2 += sT0[r + 2];
        sT0[r + 3] = fexp2(sT0[r + 3]); s3 += sT0[r + 3];
        sT1[r]     = fexp2(sT1[r]);     s0 += sT1[r];
        sT1[r + 1] = fexp2(sT1[r + 1]); s1 += sT1[r + 1];
        sT1[r + 2] = fexp2(sT1[r + 2]); s2 += sT1[r + 2];
        sT1[r + 3] = fexp2(sT1[r + 3]); s3 += sT1[r + 3];
      }
      l_run += (s0 + s1) + (s2 + s3);

      bf16x8 vf0[4], vf1[4];
#pragma unroll
      for (int ks = 0; ks < 4; ++ks) {
        vf0[ks] = *reinterpret_cast<const bf16x8*>(&Vs[ks * 1024 + fco]);
        vf1[ks] = *reinterpret_cast<const bf16x8*>(&Vs[ks * 1024 + fco + 256]);
      }

      int wpk[16];
#pragma unroll
      for (int g = 0; g < 4; ++g) {
        wpk[2 * g]     = pkbf(sT0[4 * g],     sT0[4 * g + 1]);
        wpk[2 * g + 1] = pkbf(sT0[4 * g + 2], sT0[4 * g + 3]);
        wpk[2 * (g + 4)]     = pkbf(sT1[4 * g],     sT1[4 * g + 1]);
        wpk[2 * (g + 4) + 1] = pkbf(sT1[4 * g + 2], sT1[4 * g + 3]);
      }

      // 8-shuffle exchange: lane sends exactly what its cross-half partner needs
      bf16x8 pf[4];
#pragma unroll
      for (int ks = 0; ks < 4; ++ks) {
        int send0 = hl ? wpk[4 * ks]     : wpk[4 * ks + 2];
        int send1 = hl ? wpk[4 * ks + 1] : wpk[4 * ks + 3];
        int recv0 = __shfl_xor(send0, 32);
        int recv1 = __shfl_xor(send1, 32);
        union { int i[4]; bf16x8 v; } u;
        u.i[0] = hl ? recv0 : wpk[4 * ks];
        u.i[1] = hl ? recv1 : wpk[4 * ks + 1];
        u.i[2] = hl ? wpk[4 * ks + 2] : recv0;
        u.i[3] = hl ? wpk[4 * ks + 3] : recv1;
        pf[ks] = u.v;
      }

      __builtin_amdgcn_s_setprio(1);
#pragma unroll
      for (int ks = 0; ks < 4; ++ks) {
        of0 = __builtin_amdgcn_mfma_f32_32x32x16_bf16(pf[ks], vf0[ks], of0, 0, 0, 0);
        of1 = __builtin_amdgcn_mfma_f32_32x32x16_bf16(pf[ks], vf1[ks], of1, 0, 0, 0);
      }
      __builtin_amdgcn_s_setprio(0);
    }
  }

  // ---- epilogue ----
  __syncthreads();  // all reads done; smem reusable for bounce
  float lt = l_run + __shfl_xor(l_run, 32);
  float inv = 1.0f / lt;
  if (out_mode == 0) {
    bf16* T = &smem[w * 2560];  // [64 d][32 q] stride 40
#pragma unroll
    for (int r = 0; r < 16; ++r) {
      int qloc = (r & 3) + 8 * (r >> 2) + 4 * hl;
      float invr = bpermf(qloc + (l & 32), inv);
      T[ln31 * 40 + qloc] = (bf16)(of0[r] * invr);
      T[(ln31 + 32) * 40 + qloc] = (bf16)(of1[r] * invr);
    }
#pragma unroll
    for (int i = 0; i < 4; ++i) {
      int d = (l >> 2) + 16 * i;
      int qc = (l & 3) * 8;
      bf16x8 v = *reinterpret_cast<const bf16x8*>(&T[d * 40 + qc]);
      *reinterpret_cast<bf16x8*>(Op + ((size_t)bh * HD + d) * NTOK + q0 + w * 32 + qc) = v;
    }
  } else {
#pragma unroll
    for (int r = 0; r < 16; ++r) {
      int qloc = (r & 3) + 8 * (r >> 2) + 4 * hl;
      float invr = bpermf(qloc + (l & 32), inv);
      int q = q0 + w * 32 + qloc;
      int b = bh >> 3, h = bh & 7;
      bf16* p = Op + ((size_t)(b * NTOK + q)) * DIMC + h * 64;
      p[ln31] = (bf16)(of0[r] * invr);
      p[ln31 + 32] = (bf16)(of1[r] * invr);
    }
  }
}

extern "C" void kernel_launch(void* const* d_in, const int* in_sizes, int n_in,
                              void* d_out, int out_size, void* d_ws, size_t ws_size,
                              hipStream_t stream) {
  const float* r  = (const float*)d_in[0];
  const float* z  = (const float*)d_in[1];
  const float* wr = (const float*)d_in[2];
  const float* br = (const float*)d_in[3];
  const float* wz = (const float*)d_in[4];
  const float* bz = (const float*)d_in[5];
  const float* Wq = (const float*)d_in[6];
  const float* Wk = (const float*)d_in[7];
  const float* Wv = (const float*)d_in[8];
  const float* Wa = (const float*)d_in[9];
  const float* Wp = (const float*)d_in[10];
  const float* bp = (const float*)d_in[11];

  // ws: rf 8.39M | zf 8.39M | qka 33.55M (Q,K,A,V^T) | v1t 8.39M | at2 8.39M | Wbf 2.62M
  char* ws = (char*)d_ws;
  bf16* rf   = (bf16*)ws;
  bf16* zf   = rf + (size_t)NB * NTOK * DIMC;
  bf16* qka  = zf + (size_t)NB * NTOK * DIMC;
  const size_t SLOT = (size_t)NB * NH * NTOK * HD;
  bf16* v1t = qka + 4 * SLOT;   // [bh][64][1024] (attn1 @ V)^T
  bf16* at2 = v1t + SLOT;       // [b][n][c]
  bf16* Wbf = at2 + SLOT;       // 5 x 512 x 512

  bf16* Qt = qka;
  bf16* Kt = qka + 1 * SLOT;
  bf16* At = qka + 2 * SLOT;
  bf16* vt = qka + 3 * SLOT;    // [b][512][1024] V^T (gemm<0> mat==3)

  k_ln_fused<<<dim3(16, NB, 2), 256, 0, stream>>>(r, z, wr, br, wz, bz, rf, zf);
  k_cvt5<<<dim3(256, 5), 256, 0, stream>>>(Wq, Wk, Wv, Wa, Wp, Wbf);
  k_gemm<0><<<dim3(32, 4, NB), 256, 0, stream>>>(rf, zf, Wbf, qka, nullptr, nullptr);
  // stage 1: softmax(K A^T) V -> v1t (transposed)
  k_flash10<<<512, 256, 0, stream>>>(Kt, At, vt, v1t, 0);
  // stage 2: softmax(A Q^T) v1 -> at2 [b][n][c]
  k_flash10<<<512, 256, 0, stream>>>(At, Qt, v1t, at2, 1);
  // projection + bias + residual
  k_gemm<1><<<dim3(32, 1, NB), 256, 0, stream>>>(at2, nullptr, Wbf, d_out, z, bp);
}

// Round 12
// 139.586 us; speedup vs baseline: 1.0652x; 1.0652x over previous
//
#include <hip/hip_runtime.h>
#include <hip/hip_bf16.h>
#include <stdint.h>

// AnchorAttention on MI355X. Inputs/outputs fp32; internal compute bf16 MFMA + fp32 accum.
// Pipeline: ln_fused -> cvt weights -> gemm<0> QKA+V^T (pipelined BK=32) -> flash9 x2
//           -> gemm<1> (pipelined BK=32).

using bf16 = __bf16;
typedef __bf16 bf16x4 __attribute__((ext_vector_type(4)));
typedef __bf16 bf16x8 __attribute__((ext_vector_type(8)));
typedef float f32x4 __attribute__((ext_vector_type(4)));
typedef float f32x16 __attribute__((ext_vector_type(16)));

#define DIMC 512
#define NTOK 1024
#define NB 8
#define NH 8
#define HD 64

__device__ __forceinline__ void gload_lds16(const bf16* g, bf16* l) {
  __builtin_amdgcn_global_load_lds((__attribute__((address_space(1))) void*)g,
                                   (__attribute__((address_space(3))) void*)l,
                                   16, 0, 0);
}

__device__ __forceinline__ float bpermf(int srclane, float v) {
  int i = __builtin_amdgcn_ds_bpermute(srclane << 2, __builtin_bit_cast(int, v));
  return __builtin_bit_cast(float, i);
}

__device__ __forceinline__ int pkbf(float lo, float hi) {
  unsigned short a = __builtin_bit_cast(unsigned short, (bf16)lo);
  unsigned short b = __builtin_bit_cast(unsigned short, (bf16)hi);
  return (int)((unsigned)a | ((unsigned)b << 16));
}

// raw v_exp_f32: exact 2^x
__device__ __forceinline__ float fexp2(float x) {
  float r;
  asm("v_exp_f32 %0, %1" : "=v"(r) : "v"(x));
  return r;
}

// ---------------- fused LN: stats + apply + transpose ----------------
__global__ __launch_bounds__(256) void k_ln_fused(
    const float* __restrict__ r, const float* __restrict__ z,
    const float* __restrict__ wr, const float* __restrict__ br,
    const float* __restrict__ wz, const float* __restrict__ bz,
    bf16* __restrict__ rf, bf16* __restrict__ zf) {
  __shared__ float sp[4][64], ssq[4][64];
  __shared__ float muS[64], rsS[64];
  __shared__ __align__(16) bf16 T[64 * 72];
  int n0 = blockIdx.x * 64, b = blockIdx.y, tensor = blockIdx.z;
  const float* x   = tensor ? z  : r;
  const float* w   = tensor ? wz : wr;
  const float* bia = tensor ? bz : br;
  bf16* out = tensor ? zf : rf;
  int tid = threadIdx.x;

  {
    int n = tid & 63, grp = tid >> 6;
    const float* xp = x + ((size_t)(b * DIMC + grp * 128)) * NTOK + n0 + n;
    float s = 0.f, ss = 0.f;
#pragma unroll 8
    for (int c = 0; c < 128; ++c) {
      float v = xp[(size_t)c * NTOK];
      s += v; ss += v * v;
    }
    sp[grp][n] = s; ssq[grp][n] = ss;
  }
  __syncthreads();
  if (tid < 64) {
    float s  = sp[0][tid] + sp[1][tid] + sp[2][tid] + sp[3][tid];
    float ss = ssq[0][tid] + ssq[1][tid] + ssq[2][tid] + ssq[3][tid];
    float m = s * (1.0f / DIMC);
    muS[tid] = m;
    rsS[tid] = rsqrtf(ss * (1.0f / DIMC) - m * m + 1e-5f);
  }
  __syncthreads();

  int cl = tid >> 3;
  int nl = (tid & 7) * 8;
  for (int cs = 0; cs < 8; ++cs) {
    int c0 = cs * 64;
#pragma unroll
    for (int pass = 0; pass < 2; ++pass) {
      int c = c0 + pass * 32 + cl;
      float wc = w[c], bc = bia[c];
      const float* src = x + ((size_t)(b * DIMC + c)) * NTOK + n0 + nl;
      float4 v0 = *reinterpret_cast<const float4*>(src);
      float4 v1 = *reinterpret_cast<const float4*>(src + 4);
      float vv[8] = {v0.x, v0.y, v0.z, v0.w, v1.x, v1.y, v1.z, v1.w};
#pragma unroll
      for (int j = 0; j < 8; ++j) {
        int n = nl + j;
        float val = (vv[j] - muS[n]) * rsS[n] * wc + bc;
        T[n * 72 + pass * 32 + cl] = (bf16)val;
      }
    }
    __syncthreads();
#pragma unroll
    for (int pass = 0; pass < 2; ++pass) {
      int n = pass * 32 + cl;
      bf16x8 o;
#pragma unroll
      for (int j = 0; j < 8; ++j) o[j] = T[n * 72 + nl + j];
      *reinterpret_cast<bf16x8*>(out + ((size_t)(b * NTOK + n0 + n)) * DIMC + c0 + nl) = o;
    }
    __syncthreads();
  }
}

// ---------------- weight convert fp32 -> bf16, 5 matrices ----------------
__global__ __launch_bounds__(256) void k_cvt5(
    const float* __restrict__ W0, const float* __restrict__ W1,
    const float* __restrict__ W2, const float* __restrict__ W3,
    const float* __restrict__ W4, bf16* __restrict__ out) {
  int m = blockIdx.y;
  const float* W = (m == 0) ? W0 : (m == 1) ? W1 : (m == 2) ? W2 : (m == 3) ? W3 : W4;
  bf16* o = out + (size_t)m * DIMC * DIMC;
  int i = blockIdx.x * 256 + threadIdx.x;
  float4 v = reinterpret_cast<const float4*>(W)[i];
  bf16x4 b;
  b[0] = (bf16)v.x; b[1] = (bf16)v.y; b[2] = (bf16)v.z; b[3] = (bf16)v.w;
  *reinterpret_cast<bf16x4*>(o + (size_t)i * 4) = b;
}

// ---------------- GEMM (bt), 128x128 tile, BK=32, double-buffered 1-barrier pipeline ----------------
// MODE 0: mat 0=Q 1=K 2=A (act x W -> qka[mat][b][h][n][d]); mat 3 = V^T (Wv x zf -> vt[b][d][n])
// MODE 1: Wproj x at2 -> d_out[b][o][n] + bias + residual z (fp32)
template <int MODE>
__global__ __launch_bounds__(256) void k_gemm(
    const bf16* __restrict__ actA, const bf16* __restrict__ zf,
    const bf16* __restrict__ Wbf,
    void* __restrict__ outbase,
    const float* __restrict__ zres, const float* __restrict__ bproj) {
  __shared__ __align__(16) bf16 As[2][128 * 32];
  __shared__ __align__(16) bf16 Bs[2][128 * 32];
  int b = blockIdx.z;
  const bf16 *Ap, *Bp;
  int m0, n0;
  int mat = (MODE == 0) ? blockIdx.y : -1;
  if (MODE == 0 && mat < 3) {
    Ap = (mat < 2 ? actA : zf) + (size_t)b * NTOK * DIMC;
    int widx = (mat == 2) ? 3 : mat;
    Bp = Wbf + (size_t)widx * DIMC * DIMC;
    m0 = (blockIdx.x >> 2) * 128;
    n0 = (blockIdx.x & 3) * 128;
  } else {
    Ap = Wbf + (size_t)(MODE == 1 ? 4 : 2) * DIMC * DIMC;
    Bp = (MODE == 1 ? actA : zf) + (size_t)b * NTOK * DIMC;
    m0 = (blockIdx.x >> 3) * 128;
    n0 = (blockIdx.x & 7) * 128;
  }
  int tid = threadIdx.x;
  int w = tid >> 6, l = tid & 63;
  int wm = (w >> 1) * 64, wn = (w & 1) * 64;
  int lr = l & 15, lg = l >> 4;
  int srow = l >> 2;          // 0..15 staging row within 16-row group
  int scol = (l & 3) * 8;     // staging k element offset
  f32x4 acc[4][4] = {};

  // stage K-slab kt into buffer d (one gload pair per wave per 16-row group)
  auto STAGE = [&](int kt, int d) {
    int k0 = kt * 32;
#pragma unroll
    for (int q = 0; q < 2; ++q) {
      int rowA = w * 32 + q * 16 + srow;
      gload_lds16(Ap + (size_t)(m0 + rowA) * DIMC + k0 + scol, &As[d][(w * 32 + q * 16) * 32]);
      gload_lds16(Bp + (size_t)(n0 + rowA) * DIMC + k0 + scol, &Bs[d][(w * 32 + q * 16) * 32]);
    }
  };

  STAGE(0, 0);  // prologue

  for (int kt = 0; kt < 16; ++kt) {
    __syncthreads();  // stage(kt) drained; reads of buf(kt-1) complete
    int d = kt & 1;
    if (kt + 1 < 16) STAGE(kt + 1, d ^ 1);  // prefetch flies under this slab's MFMA

    bf16x8 af[4], bfr[4];
#pragma unroll
    for (int i = 0; i < 4; ++i)
      af[i] = *reinterpret_cast<const bf16x8*>(&As[d][(wm + 16 * i + lr) * 32 + lg * 8]);
#pragma unroll
    for (int j = 0; j < 4; ++j)
      bfr[j] = *reinterpret_cast<const bf16x8*>(&Bs[d][(wn + 16 * j + lr) * 32 + lg * 8]);
#pragma unroll
    for (int i = 0; i < 4; ++i)
#pragma unroll
      for (int j = 0; j < 4; ++j)
        acc[i][j] = __builtin_amdgcn_mfma_f32_16x16x32_bf16(af[i], bfr[j], acc[i][j], 0, 0, 0);
  }

  const size_t SLOT = (size_t)NB * NH * NTOK * HD;
#pragma unroll
  for (int i = 0; i < 4; ++i) {
#pragma unroll
    for (int j = 0; j < 4; ++j) {
#pragma unroll
      for (int rr = 0; rr < 4; ++rr) {
        int mm = m0 + wm + 16 * i + lg * 4 + rr;
        int nn = n0 + wn + 16 * j + lr;
        if (MODE == 0 && mat < 3) {
          bf16* outp = (bf16*)outbase + (size_t)mat * SLOT + (size_t)b * (NH * NTOK * HD);
          outp[((size_t)((nn >> 6) * NTOK + mm)) * HD + (nn & 63)] = (bf16)acc[i][j][rr];
        } else if (MODE == 0) {
          bf16* outp = (bf16*)outbase + 3 * SLOT + (size_t)b * DIMC * NTOK;
          outp[(size_t)mm * NTOK + nn] = (bf16)acc[i][j][rr];
        } else {
          float* outp = (float*)outbase + (size_t)b * DIMC * NTOK;
          const float* zp = zres + (size_t)b * DIMC * NTOK;
          size_t idx = (size_t)mm * NTOK + nn;
          outp[idx] = acc[i][j][rr] + bproj[mm] + zp[idx];
        }
      }
    }
  }
}

// ---------------- flash9: full-KV flash, fixed-max softmax, 8-shuffle P exchange ----------------
// 4 warps x QBLK=32 (block = 128 q), KVBLK=64, 16 tiles. Swapped QK^T; exp2 fixed max M=16
// folded into MFMA C-init (exact power-of-two scaling cancels in O/l). Fragment-linear LDS
// staging (conflict-free), double-buffered, 1 barrier/tile. Cross-half l-reduce deferred.
// grid 512: xcd=id&7, qt=(id>>3)&7, bh=((id&7)<<3)|(id>>6) -> K/V L2-resident per XCD.
// out_mode 0: O^T -> [bh][d][n] (LDS bounce); out_mode 1: [b][n][h*64+d].
__global__ __launch_bounds__(256) void k_flash9(
    const bf16* __restrict__ Qp, const bf16* __restrict__ Kp,
    const bf16* __restrict__ Vtp, bf16* __restrict__ Op, int out_mode) {
  __shared__ __align__(16) bf16 smem[16384];
  int tid = threadIdx.x;
  int w = tid >> 6, l = tid & 63;
  int hl = l >> 5, ln31 = l & 31;
  int id = blockIdx.x;
  int qt = (id >> 3) & 7;
  int bh = ((id & 7) << 3) | (id >> 6);
  int q0 = qt * 128;
  const bf16* Qb = Qp + (size_t)bh * NTOK * HD;
  const bf16* Kb = Kp + (size_t)bh * NTOK * HD;
  const bf16* Vb = Vtp + (size_t)bh * HD * NTOK;

  const float QS = 0.125f * 1.44269504088896340736f;
  bf16x8 qf[4];
  int qrow = q0 + w * 32 + ln31;
#pragma unroll
  for (int s = 0; s < 4; ++s) {
    bf16x8 raw = *reinterpret_cast<const bf16x8*>(Qb + (size_t)qrow * 64 + 16 * s + 8 * hl);
#pragma unroll
    for (int j = 0; j < 8; ++j) qf[s][j] = (bf16)((float)raw[j] * QS);
  }

  int koff0 = w * 16;
  int koff1 = w * 16 + 8;
  int fco = hl * 512 + ln31 * 8;

  // prologue: stage tile 0 into buf 0
  gload_lds16(Kb + (size_t)l * 64 + koff0, &smem[(2 * w) * 512]);
  gload_lds16(Kb + (size_t)l * 64 + koff1, &smem[(2 * w + 1) * 512]);
  gload_lds16(Vb + (size_t)l * 1024 + koff0, &smem[4096 + (2 * w) * 512]);
  gload_lds16(Vb + (size_t)l * 1024 + koff1, &smem[4096 + (2 * w + 1) * 512]);

  float l_run = 0.f;
  f32x16 of0{}, of1{};

#pragma unroll 1
  for (int kt = 0; kt < 16; ++kt) {
    __syncthreads();  // stage(kt) ready; reads of buf(kt-1) complete
    int buf = (kt & 1) ? 8192 : 0;

    if (kt + 1 < 16) {
      int k0n = (kt + 1) * 64;
      int nb = buf ^ 8192;
      gload_lds16(Kb + (size_t)(k0n + l) * 64 + koff0, &smem[nb + (2 * w) * 512]);
      gload_lds16(Kb + (size_t)(k0n + l) * 64 + koff1, &smem[nb + (2 * w + 1) * 512]);
      gload_lds16(Vb + (size_t)l * 1024 + k0n + koff0, &smem[nb + 4096 + (2 * w) * 512]);
      gload_lds16(Vb + (size_t)l * 1024 + k0n + koff1, &smem[nb + 4096 + (2 * w + 1) * 512]);
    }

    const bf16* Ks = &smem[buf];
    const bf16* Vs = &smem[buf + 4096];

    bf16x8 kf0[4], kf1[4];
#pragma unroll
    for (int s = 0; s < 4; ++s) {
      kf0[s] = *reinterpret_cast<const bf16x8*>(&Ks[s * 1024 + fco]);
      kf1[s] = *reinterpret_cast<const bf16x8*>(&Ks[s * 1024 + fco + 256]);
    }

    f32x16 sT0, sT1;
#pragma unroll
    for (int r = 0; r < 16; ++r) { sT0[r] = -16.0f; sT1[r] = -16.0f; }
    __builtin_amdgcn_s_setprio(1);
#pragma unroll
    for (int s = 0; s < 4; ++s) {
      sT0 = __builtin_amdgcn_mfma_f32_32x32x16_bf16(kf0[s], qf[s], sT0, 0, 0, 0);
      sT1 = __builtin_amdgcn_mfma_f32_32x32x16_bf16(kf1[s], qf[s], sT1, 0, 0, 0);
    }
    __builtin_amdgcn_s_setprio(0);

    float s0 = 0.f, s1 = 0.f, s2 = 0.f, s3 = 0.f;
#pragma unroll
    for (int r = 0; r < 16; r += 4) {
      sT0[r]     = fexp2(sT0[r]);     s0 += sT0[r];
      sT0[r + 1] = fexp2(sT0[r + 1]); s1 += sT0[r + 1];
      sT0[r + 2] = fexp2(sT0[r + 2]); s2 += sT0[r + 2];
      sT0[r + 3] = fexp2(sT0[r + 3]); s3 += sT0[r + 3];
      sT1[r]     = fexp2(sT1[r]);     s0 += sT1[r];
      sT1[r + 1] = fexp2(sT1[r + 1]); s1 += sT1[r + 1];
      sT1[r + 2] = fexp2(sT1[r + 2]); s2 += sT1[r + 2];
      sT1[r + 3] = fexp2(sT1[r + 3]); s3 += sT1[r + 3];
    }
    l_run += (s0 + s1) + (s2 + s3);

    bf16x8 vf0[4], vf1[4];
#pragma unroll
    for (int ks = 0; ks < 4; ++ks) {
      vf0[ks] = *reinterpret_cast<const bf16x8*>(&Vs[ks * 1024 + fco]);
      vf1[ks] = *reinterpret_cast<const bf16x8*>(&Vs[ks * 1024 + fco + 256]);
    }

    int wpk[16];
#pragma unroll
    for (int g = 0; g < 4; ++g) {
      wpk[2 * g]     = pkbf(sT0[4 * g],     sT0[4 * g + 1]);
      wpk[2 * g + 1] = pkbf(sT0[4 * g + 2], sT0[4 * g + 3]);
      wpk[2 * (g + 4)]     = pkbf(sT1[4 * g],     sT1[4 * g + 1]);
      wpk[2 * (g + 4) + 1] = pkbf(sT1[4 * g + 2], sT1[4 * g + 3]);
    }

    // 8-shuffle exchange: lane sends exactly what its cross-half partner needs
    bf16x8 pf[4];
#pragma unroll
    for (int ks = 0; ks < 4; ++ks) {
      int send0 = hl ? wpk[4 * ks]     : wpk[4 * ks + 2];
      int send1 = hl ? wpk[4 * ks + 1] : wpk[4 * ks + 3];
      int recv0 = __shfl_xor(send0, 32);
      int recv1 = __shfl_xor(send1, 32);
      union { int i[4]; bf16x8 v; } u;
      u.i[0] = hl ? recv0 : wpk[4 * ks];
      u.i[1] = hl ? recv1 : wpk[4 * ks + 1];
      u.i[2] = hl ? wpk[4 * ks + 2] : recv0;
      u.i[3] = hl ? wpk[4 * ks + 3] : recv1;
      pf[ks] = u.v;
    }

    __builtin_amdgcn_s_setprio(1);
#pragma unroll
    for (int ks = 0; ks < 4; ++ks) {
      of0 = __builtin_amdgcn_mfma_f32_32x32x16_bf16(pf[ks], vf0[ks], of0, 0, 0, 0);
      of1 = __builtin_amdgcn_mfma_f32_32x32x16_bf16(pf[ks], vf1[ks], of1, 0, 0, 0);
    }
    __builtin_amdgcn_s_setprio(0);
  }

  // ---- epilogue ----
  __syncthreads();  // all reads done; smem reusable for bounce
  float lt = l_run + __shfl_xor(l_run, 32);
  float inv = 1.0f / lt;
  if (out_mode == 0) {
    bf16* T = &smem[w * 2560];  // [64 d][32 q] stride 40
#pragma unroll
    for (int r = 0; r < 16; ++r) {
      int qloc = (r & 3) + 8 * (r >> 2) + 4 * hl;
      float invr = bpermf(qloc + (l & 32), inv);
      T[ln31 * 40 + qloc] = (bf16)(of0[r] * invr);
      T[(ln31 + 32) * 40 + qloc] = (bf16)(of1[r] * invr);
    }
#pragma unroll
    for (int i = 0; i < 4; ++i) {
      int d = (l >> 2) + 16 * i;
      int qc = (l & 3) * 8;
      bf16x8 v = *reinterpret_cast<const bf16x8*>(&T[d * 40 + qc]);
      *reinterpret_cast<bf16x8*>(Op + ((size_t)bh * HD + d) * NTOK + q0 + w * 32 + qc) = v;
    }
  } else {
#pragma unroll
    for (int r = 0; r < 16; ++r) {
      int qloc = (r & 3) + 8 * (r >> 2) + 4 * hl;
      float invr = bpermf(qloc + (l & 32), inv);
      int q = q0 + w * 32 + qloc;
      int b = bh >> 3, h = bh & 7;
      bf16* p = Op + ((size_t)(b * NTOK + q)) * DIMC + h * 64;
      p[ln31] = (bf16)(of0[r] * invr);
      p[ln31 + 32] = (bf16)(of1[r] * invr);
    }
  }
}

extern "C" void kernel_launch(void* const* d_in, const int* in_sizes, int n_in,
                              void* d_out, int out_size, void* d_ws, size_t ws_size,
                              hipStream_t stream) {
  const float* r  = (const float*)d_in[0];
  const float* z  = (const float*)d_in[1];
  const float* wr = (const float*)d_in[2];
  const float* br = (const float*)d_in[3];
  const float* wz = (const float*)d_in[4];
  const float* bz = (const float*)d_in[5];
  const float* Wq = (const float*)d_in[6];
  const float* Wk = (const float*)d_in[7];
  const float* Wv = (const float*)d_in[8];
  const float* Wa = (const float*)d_in[9];
  const float* Wp = (const float*)d_in[10];
  const float* bp = (const float*)d_in[11];

  // ws: rf 8.39M | zf 8.39M | qka 33.55M (Q,K,A,V^T) | v1t 8.39M | at2 8.39M | Wbf 2.62M
  char* ws = (char*)d_ws;
  bf16* rf   = (bf16*)ws;
  bf16* zf   = rf + (size_t)NB * NTOK * DIMC;
  bf16* qka  = zf + (size_t)NB * NTOK * DIMC;
  const size_t SLOT = (size_t)NB * NH * NTOK * HD;
  bf16* v1t = qka + 4 * SLOT;   // [bh][64][1024] (attn1 @ V)^T
  bf16* at2 = v1t + SLOT;       // [b][n][c]
  bf16* Wbf = at2 + SLOT;       // 5 x 512 x 512

  bf16* Qt = qka;
  bf16* Kt = qka + 1 * SLOT;
  bf16* At = qka + 2 * SLOT;
  bf16* vt = qka + 3 * SLOT;    // [b][512][1024] V^T (gemm<0> mat==3)

  k_ln_fused<<<dim3(16, NB, 2), 256, 0, stream>>>(r, z, wr, br, wz, bz, rf, zf);
  k_cvt5<<<dim3(256, 5), 256, 0, stream>>>(Wq, Wk, Wv, Wa, Wp, Wbf);
  k_gemm<0><<<dim3(32, 4, NB), 256, 0, stream>>>(rf, zf, Wbf, qka, nullptr, nullptr);
  // stage 1: softmax(K A^T) V -> v1t (transposed)
  k_flash9<<<512, 256, 0, stream>>>(Kt, At, vt, v1t, 0);
  // stage 2: softmax(A Q^T) v1 -> at2 [b][n][c]
  k_flash9<<<512, 256, 0, stream>>>(At, Qt, v1t, at2, 1);
  // projection + bias + residual
  k_gemm<1><<<dim3(32, 1, NB), 256, 0, stream>>>(at2, nullptr, Wbf, d_out, z, bp);
}

// Round 13
// 134.456 us; speedup vs baseline: 1.1059x; 1.0382x over previous
//
#include <hip/hip_runtime.h>
#include <hip/hip_bf16.h>
#include <stdint.h>

// AnchorAttention on MI355X. Inputs/outputs fp32; internal compute bf16 MFMA + fp32 accum.
// Pipeline: ln_fused (1-global-read, LDS stash) -> cvt weights -> gemm<0> QKA+V^T (BK=64)
//           -> flash9 x2 -> gemm<1> (BK=64).

using bf16 = __bf16;
typedef __bf16 bf16x4 __attribute__((ext_vector_type(4)));
typedef __bf16 bf16x8 __attribute__((ext_vector_type(8)));
typedef float f32x4 __attribute__((ext_vector_type(4)));
typedef float f32x16 __attribute__((ext_vector_type(16)));

#define DIMC 512
#define NTOK 1024
#define NB 8
#define NH 8
#define HD 64

__device__ __forceinline__ void gload_lds16(const bf16* g, bf16* l) {
  __builtin_amdgcn_global_load_lds((__attribute__((address_space(1))) void*)g,
                                   (__attribute__((address_space(3))) void*)l,
                                   16, 0, 0);
}

__device__ __forceinline__ float bpermf(int srclane, float v) {
  int i = __builtin_amdgcn_ds_bpermute(srclane << 2, __builtin_bit_cast(int, v));
  return __builtin_bit_cast(float, i);
}

__device__ __forceinline__ int pkbf(float lo, float hi) {
  unsigned short a = __builtin_bit_cast(unsigned short, (bf16)lo);
  unsigned short b = __builtin_bit_cast(unsigned short, (bf16)hi);
  return (int)((unsigned)a | ((unsigned)b << 16));
}

// raw v_exp_f32: exact 2^x
__device__ __forceinline__ float fexp2(float x) {
  float r;
  asm("v_exp_f32 %0, %1" : "=v"(r) : "v"(x));
  return r;
}

// ---------------- fused LN: stats + bf16 LDS stash + apply + transpose (ONE global read) ----
// grid (16 n-tiles, NB, 2 tensors), 256 threads, 1 block/CU.
// Phase A: per-token sum/sumsq over 4 channel-groups (coalesced) while stashing x as bf16
//          into xbf[c][n] (row stride 68: 8B-aligned rows, near-floor bank behavior).
// Phase B: LN apply reading xbf (2x b64 per 8-token chunk) + [n][c] transpose via padded T.
__global__ __launch_bounds__(256) void k_ln_fused(
    const float* __restrict__ r, const float* __restrict__ z,
    const float* __restrict__ wr, const float* __restrict__ br,
    const float* __restrict__ wz, const float* __restrict__ bz,
    bf16* __restrict__ rf, bf16* __restrict__ zf) {
  __shared__ float sp[4][64], ssq[4][64];
  __shared__ float muS[64], rsS[64];
  __shared__ __align__(16) bf16 xbf[512 * 68];  // [c][token], stride 68 (~70KB)
  __shared__ __align__(16) bf16 T[64 * 72];
  int n0 = blockIdx.x * 64, b = blockIdx.y, tensor = blockIdx.z;
  const float* x   = tensor ? z  : r;
  const float* w   = tensor ? wz : wr;
  const float* bia = tensor ? bz : br;
  bf16* out = tensor ? zf : rf;
  int tid = threadIdx.x;

  // Phase A: stats + stash
  {
    int n = tid & 63, grp = tid >> 6;
    const float* xp = x + ((size_t)(b * DIMC + grp * 128)) * NTOK + n0 + n;
    float s = 0.f, ss = 0.f;
#pragma unroll 8
    for (int c = 0; c < 128; ++c) {
      float v = xp[(size_t)c * NTOK];
      s += v; ss += v * v;
      xbf[(grp * 128 + c) * 68 + n] = (bf16)v;
    }
    sp[grp][n] = s; ssq[grp][n] = ss;
  }
  __syncthreads();
  if (tid < 64) {
    float s  = sp[0][tid] + sp[1][tid] + sp[2][tid] + sp[3][tid];
    float ss = ssq[0][tid] + ssq[1][tid] + ssq[2][tid] + ssq[3][tid];
    float m = s * (1.0f / DIMC);
    muS[tid] = m;
    rsS[tid] = rsqrtf(ss * (1.0f / DIMC) - m * m + 1e-5f);
  }
  __syncthreads();

  // Phase B: apply from LDS stash + transpose
  int cl = tid >> 3;          // 0..31
  int nl = (tid & 7) * 8;     // 0..56
  for (int cs = 0; cs < 8; ++cs) {
    int c0 = cs * 64;
#pragma unroll
    for (int pass = 0; pass < 2; ++pass) {
      int c = c0 + pass * 32 + cl;
      float wc = w[c], bc = bia[c];
      const bf16* src = &xbf[c * 68 + nl];
      bf16x4 v0 = *reinterpret_cast<const bf16x4*>(src);
      bf16x4 v1 = *reinterpret_cast<const bf16x4*>(src + 4);
      float vv[8] = {(float)v0[0], (float)v0[1], (float)v0[2], (float)v0[3],
                     (float)v1[0], (float)v1[1], (float)v1[2], (float)v1[3]};
#pragma unroll
      for (int j = 0; j < 8; ++j) {
        int n = nl + j;
        float val = (vv[j] - muS[n]) * rsS[n] * wc + bc;
        T[n * 72 + pass * 32 + cl] = (bf16)val;
      }
    }
    __syncthreads();
#pragma unroll
    for (int pass = 0; pass < 2; ++pass) {
      int n = pass * 32 + cl;
      bf16x8 o;
#pragma unroll
      for (int j = 0; j < 8; ++j) o[j] = T[n * 72 + nl + j];
      *reinterpret_cast<bf16x8*>(out + ((size_t)(b * NTOK + n0 + n)) * DIMC + c0 + nl) = o;
    }
    __syncthreads();
  }
}

// ---------------- weight convert fp32 -> bf16, 5 matrices ----------------
__global__ __launch_bounds__(256) void k_cvt5(
    const float* __restrict__ W0, const float* __restrict__ W1,
    const float* __restrict__ W2, const float* __restrict__ W3,
    const float* __restrict__ W4, bf16* __restrict__ out) {
  int m = blockIdx.y;
  const float* W = (m == 0) ? W0 : (m == 1) ? W1 : (m == 2) ? W2 : (m == 3) ? W3 : W4;
  bf16* o = out + (size_t)m * DIMC * DIMC;
  int i = blockIdx.x * 256 + threadIdx.x;
  float4 v = reinterpret_cast<const float4*>(W)[i];
  bf16x4 b;
  b[0] = (bf16)v.x; b[1] = (bf16)v.y; b[2] = (bf16)v.z; b[3] = (bf16)v.w;
  *reinterpret_cast<bf16x4*>(o + (size_t)i * 4) = b;
}

// ---------------- GEMM (bt), 128x128 tile, BK=64 as two [128][32] LDS panels (R10 winner) ----
// MODE 0: mat 0=Q 1=K 2=A (act x W -> qka[mat][b][h][n][d]); mat 3 = V^T (Wv x zf -> vt[b][d][n])
// MODE 1: Wproj x at2 -> d_out[b][o][n] + bias + residual z (fp32)
template <int MODE>
__global__ __launch_bounds__(256) void k_gemm(
    const bf16* __restrict__ actA, const bf16* __restrict__ zf,
    const bf16* __restrict__ Wbf,
    void* __restrict__ outbase,
    const float* __restrict__ zres, const float* __restrict__ bproj) {
  __shared__ __align__(16) bf16 As[2 * 128 * 32];  // [panel s][row][32]
  __shared__ __align__(16) bf16 Bs[2 * 128 * 32];
  int b = blockIdx.z;
  const bf16 *Ap, *Bp;
  int m0, n0;
  int mat = (MODE == 0) ? blockIdx.y : -1;
  if (MODE == 0 && mat < 3) {
    Ap = (mat < 2 ? actA : zf) + (size_t)b * NTOK * DIMC;
    int widx = (mat == 2) ? 3 : mat;
    Bp = Wbf + (size_t)widx * DIMC * DIMC;
    m0 = (blockIdx.x >> 2) * 128;
    n0 = (blockIdx.x & 3) * 128;
  } else {
    Ap = Wbf + (size_t)(MODE == 1 ? 4 : 2) * DIMC * DIMC;
    Bp = (MODE == 1 ? actA : zf) + (size_t)b * NTOK * DIMC;
    m0 = (blockIdx.x >> 3) * 128;
    n0 = (blockIdx.x & 7) * 128;
  }
  int tid = threadIdx.x;
  int w = tid >> 6, l = tid & 63;
  int wm = (w >> 1) * 64, wn = (w & 1) * 64;
  int lr = l & 15, lg = l >> 4;
  int srow = l >> 2;
  int scol = (l & 3) * 8;
  f32x4 acc[4][4] = {};

  for (int kt = 0; kt < 8; ++kt) {
    int k0 = kt * 64;
#pragma unroll
    for (int s = 0; s < 2; ++s) {
#pragma unroll
      for (int q = 0; q < 2; ++q) {
        int rowA = w * 32 + q * 16 + srow;
        gload_lds16(Ap + (size_t)(m0 + rowA) * DIMC + k0 + s * 32 + scol,
                    &As[s * 4096 + (w * 32 + q * 16) * 32]);
        gload_lds16(Bp + (size_t)(n0 + rowA) * DIMC + k0 + s * 32 + scol,
                    &Bs[s * 4096 + (w * 32 + q * 16) * 32]);
      }
    }
    __syncthreads();
#pragma unroll
    for (int s = 0; s < 2; ++s) {
      bf16x8 af[4], bfr[4];
#pragma unroll
      for (int i = 0; i < 4; ++i)
        af[i] = *reinterpret_cast<const bf16x8*>(&As[s * 4096 + (wm + 16 * i + lr) * 32 + lg * 8]);
#pragma unroll
      for (int j = 0; j < 4; ++j)
        bfr[j] = *reinterpret_cast<const bf16x8*>(&Bs[s * 4096 + (wn + 16 * j + lr) * 32 + lg * 8]);
#pragma unroll
      for (int i = 0; i < 4; ++i)
#pragma unroll
        for (int j = 0; j < 4; ++j)
          acc[i][j] = __builtin_amdgcn_mfma_f32_16x16x32_bf16(af[i], bfr[j], acc[i][j], 0, 0, 0);
    }
    __syncthreads();
  }

  const size_t SLOT = (size_t)NB * NH * NTOK * HD;
#pragma unroll
  for (int i = 0; i < 4; ++i) {
#pragma unroll
    for (int j = 0; j < 4; ++j) {
#pragma unroll
      for (int rr = 0; rr < 4; ++rr) {
        int mm = m0 + wm + 16 * i + lg * 4 + rr;
        int nn = n0 + wn + 16 * j + lr;
        if (MODE == 0 && mat < 3) {
          bf16* outp = (bf16*)outbase + (size_t)mat * SLOT + (size_t)b * (NH * NTOK * HD);
          outp[((size_t)((nn >> 6) * NTOK + mm)) * HD + (nn & 63)] = (bf16)acc[i][j][rr];
        } else if (MODE == 0) {
          bf16* outp = (bf16*)outbase + 3 * SLOT + (size_t)b * DIMC * NTOK;
          outp[(size_t)mm * NTOK + nn] = (bf16)acc[i][j][rr];
        } else {
          float* outp = (float*)outbase + (size_t)b * DIMC * NTOK;
          const float* zp = zres + (size_t)b * DIMC * NTOK;
          size_t idx = (size_t)mm * NTOK + nn;
          outp[idx] = acc[i][j][rr] + bproj[mm] + zp[idx];
        }
      }
    }
  }
}

// ---------------- flash9: full-KV flash, fixed-max softmax, 8-shuffle P exchange ----------------
// 4 warps x QBLK=32 (block = 128 q), KVBLK=64, 16 tiles. Swapped QK^T; exp2 fixed max M=16
// folded into MFMA C-init (exact power-of-two scaling cancels in O/l). Fragment-linear LDS
// staging (conflict-free), double-buffered, 1 barrier/tile. Cross-half l-reduce deferred.
// grid 512: xcd=id&7, qt=(id>>3)&7, bh=((id&7)<<3)|(id>>6) -> K/V L2-resident per XCD.
// out_mode 0: O^T -> [bh][d][n] (LDS bounce); out_mode 1: [b][n][h*64+d].
__global__ __launch_bounds__(256) void k_flash9(
    const bf16* __restrict__ Qp, const bf16* __restrict__ Kp,
    const bf16* __restrict__ Vtp, bf16* __restrict__ Op, int out_mode) {
  __shared__ __align__(16) bf16 smem[16384];
  int tid = threadIdx.x;
  int w = tid >> 6, l = tid & 63;
  int hl = l >> 5, ln31 = l & 31;
  int id = blockIdx.x;
  int qt = (id >> 3) & 7;
  int bh = ((id & 7) << 3) | (id >> 6);
  int q0 = qt * 128;
  const bf16* Qb = Qp + (size_t)bh * NTOK * HD;
  const bf16* Kb = Kp + (size_t)bh * NTOK * HD;
  const bf16* Vb = Vtp + (size_t)bh * HD * NTOK;

  const float QS = 0.125f * 1.44269504088896340736f;
  bf16x8 qf[4];
  int qrow = q0 + w * 32 + ln31;
#pragma unroll
  for (int s = 0; s < 4; ++s) {
    bf16x8 raw = *reinterpret_cast<const bf16x8*>(Qb + (size_t)qrow * 64 + 16 * s + 8 * hl);
#pragma unroll
    for (int j = 0; j < 8; ++j) qf[s][j] = (bf16)((float)raw[j] * QS);
  }

  int koff0 = w * 16;
  int koff1 = w * 16 + 8;
  int fco = hl * 512 + ln31 * 8;

  // prologue: stage tile 0 into buf 0
  gload_lds16(Kb + (size_t)l * 64 + koff0, &smem[(2 * w) * 512]);
  gload_lds16(Kb + (size_t)l * 64 + koff1, &smem[(2 * w + 1) * 512]);
  gload_lds16(Vb + (size_t)l * 1024 + koff0, &smem[4096 + (2 * w) * 512]);
  gload_lds16(Vb + (size_t)l * 1024 + koff1, &smem[4096 + (2 * w + 1) * 512]);

  float l_run = 0.f;
  f32x16 of0{}, of1{};

#pragma unroll 1
  for (int kt = 0; kt < 16; ++kt) {
    __syncthreads();  // stage(kt) ready; reads of buf(kt-1) complete
    int buf = (kt & 1) ? 8192 : 0;

    if (kt + 1 < 16) {
      int k0n = (kt + 1) * 64;
      int nb = buf ^ 8192;
      gload_lds16(Kb + (size_t)(k0n + l) * 64 + koff0, &smem[nb + (2 * w) * 512]);
      gload_lds16(Kb + (size_t)(k0n + l) * 64 + koff1, &smem[nb + (2 * w + 1) * 512]);
      gload_lds16(Vb + (size_t)l * 1024 + k0n + koff0, &smem[nb + 4096 + (2 * w) * 512]);
      gload_lds16(Vb + (size_t)l * 1024 + k0n + koff1, &smem[nb + 4096 + (2 * w + 1) * 512]);
    }

    const bf16* Ks = &smem[buf];
    const bf16* Vs = &smem[buf + 4096];

    bf16x8 kf0[4], kf1[4];
#pragma unroll
    for (int s = 0; s < 4; ++s) {
      kf0[s] = *reinterpret_cast<const bf16x8*>(&Ks[s * 1024 + fco]);
      kf1[s] = *reinterpret_cast<const bf16x8*>(&Ks[s * 1024 + fco + 256]);
    }

    f32x16 sT0, sT1;
#pragma unroll
    for (int r = 0; r < 16; ++r) { sT0[r] = -16.0f; sT1[r] = -16.0f; }
    __builtin_amdgcn_s_setprio(1);
#pragma unroll
    for (int s = 0; s < 4; ++s) {
      sT0 = __builtin_amdgcn_mfma_f32_32x32x16_bf16(kf0[s], qf[s], sT0, 0, 0, 0);
      sT1 = __builtin_amdgcn_mfma_f32_32x32x16_bf16(kf1[s], qf[s], sT1, 0, 0, 0);
    }
    __builtin_amdgcn_s_setprio(0);

    float s0 = 0.f, s1 = 0.f, s2 = 0.f, s3 = 0.f;
#pragma unroll
    for (int r = 0; r < 16; r += 4) {
      sT0[r]     = fexp2(sT0[r]);     s0 += sT0[r];
      sT0[r + 1] = fexp2(sT0[r + 1]); s1 += sT0[r + 1];
      sT0[r + 2] = fexp2(sT0[r + 2]); s2 += sT0[r + 2];
      sT0[r + 3] = fexp2(sT0[r + 3]); s3 += sT0[r + 3];
      sT1[r]     = fexp2(sT1[r]);     s0 += sT1[r];
      sT1[r + 1] = fexp2(sT1[r + 1]); s1 += sT1[r + 1];
      sT1[r + 2] = fexp2(sT1[r + 2]); s2 += sT1[r + 2];
      sT1[r + 3] = fexp2(sT1[r + 3]); s3 += sT1[r + 3];
    }
    l_run += (s0 + s1) + (s2 + s3);

    bf16x8 vf0[4], vf1[4];
#pragma unroll
    for (int ks = 0; ks < 4; ++ks) {
      vf0[ks] = *reinterpret_cast<const bf16x8*>(&Vs[ks * 1024 + fco]);
      vf1[ks] = *reinterpret_cast<const bf16x8*>(&Vs[ks * 1024 + fco + 256]);
    }

    int wpk[16];
#pragma unroll
    for (int g = 0; g < 4; ++g) {
      wpk[2 * g]     = pkbf(sT0[4 * g],     sT0[4 * g + 1]);
      wpk[2 * g + 1] = pkbf(sT0[4 * g + 2], sT0[4 * g + 3]);
      wpk[2 * (g + 4)]     = pkbf(sT1[4 * g],     sT1[4 * g + 1]);
      wpk[2 * (g + 4) + 1] = pkbf(sT1[4 * g + 2], sT1[4 * g + 3]);
    }

    // 8-shuffle exchange: lane sends exactly what its cross-half partner needs
    bf16x8 pf[4];
#pragma unroll
    for (int ks = 0; ks < 4; ++ks) {
      int send0 = hl ? wpk[4 * ks]     : wpk[4 * ks + 2];
      int send1 = hl ? wpk[4 * ks + 1] : wpk[4 * ks + 3];
      int recv0 = __shfl_xor(send0, 32);
      int recv1 = __shfl_xor(send1, 32);
      union { int i[4]; bf16x8 v; } u;
      u.i[0] = hl ? recv0 : wpk[4 * ks];
      u.i[1] = hl ? recv1 : wpk[4 * ks + 1];
      u.i[2] = hl ? wpk[4 * ks + 2] : recv0;
      u.i[3] = hl ? wpk[4 * ks + 3] : recv1;
      pf[ks] = u.v;
    }

    __builtin_amdgcn_s_setprio(1);
#pragma unroll
    for (int ks = 0; ks < 4; ++ks) {
      of0 = __builtin_amdgcn_mfma_f32_32x32x16_bf16(pf[ks], vf0[ks], of0, 0, 0, 0);
      of1 = __builtin_amdgcn_mfma_f32_32x32x16_bf16(pf[ks], vf1[ks], of1, 0, 0, 0);
    }
    __builtin_amdgcn_s_setprio(0);
  }

  // ---- epilogue ----
  __syncthreads();  // all reads done; smem reusable for bounce
  float lt = l_run + __shfl_xor(l_run, 32);
  float inv = 1.0f / lt;
  if (out_mode == 0) {
    bf16* T = &smem[w * 2560];  // [64 d][32 q] stride 40
#pragma unroll
    for (int r = 0; r < 16; ++r) {
      int qloc = (r & 3) + 8 * (r >> 2) + 4 * hl;
      float invr = bpermf(qloc + (l & 32), inv);
      T[ln31 * 40 + qloc] = (bf16)(of0[r] * invr);
      T[(ln31 + 32) * 40 + qloc] = (bf16)(of1[r] * invr);
    }
#pragma unroll
    for (int i = 0; i < 4; ++i) {
      int d = (l >> 2) + 16 * i;
      int qc = (l & 3) * 8;
      bf16x8 v = *reinterpret_cast<const bf16x8*>(&T[d * 40 + qc]);
      *reinterpret_cast<bf16x8*>(Op + ((size_t)bh * HD + d) * NTOK + q0 + w * 32 + qc) = v;
    }
  } else {
#pragma unroll
    for (int r = 0; r < 16; ++r) {
      int qloc = (r & 3) + 8 * (r >> 2) + 4 * hl;
      float invr = bpermf(qloc + (l & 32), inv);
      int q = q0 + w * 32 + qloc;
      int b = bh >> 3, h = bh & 7;
      bf16* p = Op + ((size_t)(b * NTOK + q)) * DIMC + h * 64;
      p[ln31] = (bf16)(of0[r] * invr);
      p[ln31 + 32] = (bf16)(of1[r] * invr);
    }
  }
}

extern "C" void kernel_launch(void* const* d_in, const int* in_sizes, int n_in,
                              void* d_out, int out_size, void* d_ws, size_t ws_size,
                              hipStream_t stream) {
  const float* r  = (const float*)d_in[0];
  const float* z  = (const float*)d_in[1];
  const float* wr = (const float*)d_in[2];
  const float* br = (const float*)d_in[3];
  const float* wz = (const float*)d_in[4];
  const float* bz = (const float*)d_in[5];
  const float* Wq = (const float*)d_in[6];
  const float* Wk = (const float*)d_in[7];
  const float* Wv = (const float*)d_in[8];
  const float* Wa = (const float*)d_in[9];
  const float* Wp = (const float*)d_in[10];
  const float* bp = (const float*)d_in[11];

  // ws: rf 8.39M | zf 8.39M | qka 33.55M (Q,K,A,V^T) | v1t 8.39M | at2 8.39M | Wbf 2.62M
  char* ws = (char*)d_ws;
  bf16* rf   = (bf16*)ws;
  bf16* zf   = rf + (size_t)NB * NTOK * DIMC;
  bf16* qka  = zf + (size_t)NB * NTOK * DIMC;
  const size_t SLOT = (size_t)NB * NH * NTOK * HD;
  bf16* v1t = qka + 4 * SLOT;   // [bh][64][1024] (attn1 @ V)^T
  bf16* at2 = v1t + SLOT;       // [b][n][c]
  bf16* Wbf = at2 + SLOT;       // 5 x 512 x 512

  bf16* Qt = qka;
  bf16* Kt = qka + 1 * SLOT;
  bf16* At = qka + 2 * SLOT;
  bf16* vt = qka + 3 * SLOT;    // [b][512][1024] V^T (gemm<0> mat==3)

  k_ln_fused<<<dim3(16, NB, 2), 256, 0, stream>>>(r, z, wr, br, wz, bz, rf, zf);
  k_cvt5<<<dim3(256, 5), 256, 0, stream>>>(Wq, Wk, Wv, Wa, Wp, Wbf);
  k_gemm<0><<<dim3(32, 4, NB), 256, 0, stream>>>(rf, zf, Wbf, qka, nullptr, nullptr);
  // stage 1: softmax(K A^T) V -> v1t (transposed)
  k_flash9<<<512, 256, 0, stream>>>(Kt, At, vt, v1t, 0);
  // stage 2: softmax(A Q^T) v1 -> at2 [b][n][c]
  k_flash9<<<512, 256, 0, stream>>>(At, Qt, v1t, at2, 1);
  // projection + bias + residual
  k_gemm<1><<<dim3(32, 1, NB), 256, 0, stream>>>(at2, nullptr, Wbf, d_out, z, bp);
}